// Round 1
// baseline (596.563 us; speedup 1.0000x reference)
//
#include <hip/hip_runtime.h>
#include <cmath>

#define T_SEQ 2048
#define HEADS 16
#define HS 64
#define NC 32                               // chunks of 64 along T
#define QK_ELEMS (HEADS * T_SEQ * HS)       // 2097152 floats per q/k/v buffer

// ---------------------------------------------------------------------------
// GEMM C[M][N] = A[M][K] * B[N][K]^T  (row-major A, row-major B => NT GEMM)
// 128x128 tile, BK=16, 256 threads, 8x8 per thread (2x2 blocks of 4x4).
// EPI=0: plain store to C.
// EPI=1: phi(x)=elu(x)+1 applied to q,k thirds; scatter into per-head layout
//        qkvws[((c*16+h)*2048 + t)*64 + s]  (c=0:q, 1:k, 2:v).
// ---------------------------------------------------------------------------
template<int EPI>
__global__ __launch_bounds__(256)
void gemm_nt(const float* __restrict__ A, const float* __restrict__ B,
             float* __restrict__ C, int M, int N, int K,
             float* __restrict__ qkvws)
{
  __shared__ float As[16][132];   // [k][m], stride 132 floats = 528B (16B-aligned rows)
  __shared__ float Bs[16][132];   // [k][n]
  const int tid   = threadIdx.x;
  const int tileN = blockIdx.x * 128;
  const int tileM = blockIdx.y * 128;
  const int tx = tid & 15, ty = tid >> 4;
  const int lr = tid >> 2;          // load row 0..63
  const int lc = (tid & 3) * 4;     // load col 0,4,8,12

  const float* Ap = A + (size_t)(tileM + lr) * K + lc;
  const float* Bp = B + (size_t)(tileN + lr) * K + lc;
  const size_t half = (size_t)64 * K;

  float acc[2][2][4][4] = {};

  float4 av0 = *(const float4*)(Ap);
  float4 av1 = *(const float4*)(Ap + half);
  float4 bv0 = *(const float4*)(Bp);
  float4 bv1 = *(const float4*)(Bp + half);

  for (int k0 = 0; k0 < K; k0 += 16) {
    __syncthreads();
    As[lc+0][lr]    = av0.x; As[lc+1][lr]    = av0.y; As[lc+2][lr]    = av0.z; As[lc+3][lr]    = av0.w;
    As[lc+0][lr+64] = av1.x; As[lc+1][lr+64] = av1.y; As[lc+2][lr+64] = av1.z; As[lc+3][lr+64] = av1.w;
    Bs[lc+0][lr]    = bv0.x; Bs[lc+1][lr]    = bv0.y; Bs[lc+2][lr]    = bv0.z; Bs[lc+3][lr]    = bv0.w;
    Bs[lc+0][lr+64] = bv1.x; Bs[lc+1][lr+64] = bv1.y; Bs[lc+2][lr+64] = bv1.z; Bs[lc+3][lr+64] = bv1.w;
    __syncthreads();
    if (k0 + 16 < K) {
      av0 = *(const float4*)(Ap + k0 + 16);
      av1 = *(const float4*)(Ap + k0 + 16 + half);
      bv0 = *(const float4*)(Bp + k0 + 16);
      bv1 = *(const float4*)(Bp + k0 + 16 + half);
    }
    #pragma unroll
    for (int kk = 0; kk < 16; ++kk) {
      float a[8], b[8];
      *(float4*)&a[0] = *(const float4*)&As[kk][ty * 4];
      *(float4*)&a[4] = *(const float4*)&As[kk][64 + ty * 4];
      *(float4*)&b[0] = *(const float4*)&Bs[kk][tx * 4];
      *(float4*)&b[4] = *(const float4*)&Bs[kk][64 + tx * 4];
      #pragma unroll
      for (int ib = 0; ib < 2; ++ib)
        #pragma unroll
        for (int jb = 0; jb < 2; ++jb)
          #pragma unroll
          for (int i = 0; i < 4; ++i)
            #pragma unroll
            for (int jx = 0; jx < 4; ++jx)
              acc[ib][jb][i][jx] += a[ib*4 + i] * b[jb*4 + jx];
    }
  }

  if (EPI == 0) {
    #pragma unroll
    for (int ib = 0; ib < 2; ++ib)
      #pragma unroll
      for (int i = 0; i < 4; ++i) {
        const int m = tileM + ib*64 + ty*4 + i;
        #pragma unroll
        for (int jb = 0; jb < 2; ++jb) {
          float v[4];
          #pragma unroll
          for (int jx = 0; jx < 4; ++jx) v[jx] = acc[ib][jb][i][jx];
          *(float4*)&C[(size_t)m * N + tileN + jb*64 + tx*4] = *(float4*)v;
        }
      }
  } else {
    const int c3 = tileN >> 10;                 // 0:q 1:k 2:v (uniform per block)
    #pragma unroll
    for (int jb = 0; jb < 2; ++jb) {
      const int hh = ((tileN >> 6) + jb) & 15;  // head (uniform per jb)
      float* dst = qkvws + ((size_t)(c3 * HEADS + hh) * T_SEQ) * HS;
      #pragma unroll
      for (int ib = 0; ib < 2; ++ib)
        #pragma unroll
        for (int i = 0; i < 4; ++i) {
          const int m = tileM + ib*64 + ty*4 + i;
          float v[4];
          #pragma unroll
          for (int jx = 0; jx < 4; ++jx) {
            float val = acc[ib][jb][i][jx];
            if (c3 < 2) val = (val > 0.f) ? (val + 1.f) : expf(val);  // phi = elu+1
            v[jx] = val;
          }
          *(float4*)&dst[(size_t)m * HS + tx*4] = *(float4*)v;
        }
    }
  }
}

// ---------------------------------------------------------------------------
// Per-chunk KV outer-product sums:  S_c = sum_{t in chunk} k_t (x) v_t  [64x64]
//                                   z_c = sum_{t in chunk} k_t          [64]
// grid (16 heads, 32 chunks), 256 threads. No LDS needed (k uniform, v coalesced).
// ---------------------------------------------------------------------------
__global__ __launch_bounds__(256)
void chunk_kv(const float* __restrict__ kbuf, const float* __restrict__ vbuf,
              float* __restrict__ Sc, float* __restrict__ Zc)
{
  const int h = blockIdx.x, c = blockIdx.y;
  const int tid = threadIdx.x;
  const int f = tid & 63, dg = tid >> 6;      // dg uniform per wave
  const size_t base = ((size_t)h * T_SEQ + c * 64) * HS;
  float s[16] = {};
  float z = 0.f;
  for (int t = 0; t < 64; ++t) {
    const float vv = vbuf[base + t*HS + f];
    const float* krow = kbuf + base + t*HS + dg*16;
    float kk4[16];
    #pragma unroll
    for (int r4 = 0; r4 < 4; ++r4)
      *(float4*)&kk4[r4*4] = *(const float4*)&krow[r4*4];
    #pragma unroll
    for (int r = 0; r < 16; ++r) s[r] += kk4[r] * vv;
    if (dg == 0) z += kbuf[base + t*HS + f];
  }
  float* Sp = Sc + ((size_t)h * NC + c) * (HS * HS);
  #pragma unroll
  for (int r = 0; r < 16; ++r) Sp[(dg*16 + r)*HS + f] = s[r];
  if (dg == 0) Zc[((size_t)h * NC + c) * HS + f] = z;
}

// ---------------------------------------------------------------------------
// In-place exclusive prefix scan over the 32 chunks, per head. grid=16 blocks.
// ---------------------------------------------------------------------------
__global__ __launch_bounds__(256)
void scan_chunks(float* __restrict__ Sc, float* __restrict__ Zc)
{
  const int h = blockIdx.x;
  const int tid = threadIdx.x;
  for (int e = tid; e < HS * HS; e += 256) {
    float run = 0.f;
    for (int c = 0; c < NC; ++c) {
      float* p = Sc + ((size_t)h * NC + c) * (HS * HS) + e;
      const float v = *p; *p = run; run += v;
    }
  }
  if (tid < HS) {
    float run = 0.f;
    for (int c = 0; c < NC; ++c) {
      float* p = Zc + ((size_t)h * NC + c) * HS + tid;
      const float v = *p; *p = run; run += v;
    }
  }
}

// ---------------------------------------------------------------------------
// Per-chunk output:
//   A[i][j] = (j<=i) ? q_i . k_j : 0          (intra-chunk causal scores)
//   num[i][f] = sum_j A[i][j] v_j[f] + q_i . Sprefix[:,f]
//   den[i]    = sum_j A[i][j]       + q_i . zprefix
//   xo[t][h*64+f] = num/(den+eps)             (written in [T][D] layout)
// grid (16 heads, 32 chunks), 256 threads (4 waves; wave w owns rows i=r*4+w).
// ---------------------------------------------------------------------------
__global__ __launch_bounds__(256)
void chunk_attn(const float* __restrict__ qbuf, const float* __restrict__ kbuf,
                const float* __restrict__ vbuf, const float* __restrict__ Sc,
                const float* __restrict__ Zc, float* __restrict__ xo)
{
  __shared__ float kT[HS][64];      // k transposed: kT[d][j] — conflict-free lane-j reads
  __shared__ float vl[64][HS + 1];  // v rows, +1 pad (scalar access only)
  __shared__ float Al[64][64];      // masked score tile (writes lane-consecutive, reads broadcast)
  const int h = blockIdx.x, c = blockIdx.y;
  const int tid = threadIdx.x;
  const size_t base = ((size_t)h * T_SEQ + c * 64) * HS;

  { // stage k (transposed) and v
    const int t0 = tid >> 2;
    const int cq = (tid & 3) * 4;
    #pragma unroll
    for (int it = 0; it < 4; ++it) {
      const int col = cq + it * 16;
      float kv[4]; *(float4*)kv = *(const float4*)&kbuf[base + (size_t)t0*HS + col];
      float vv[4]; *(float4*)vv = *(const float4*)&vbuf[base + (size_t)t0*HS + col];
      #pragma unroll
      for (int u = 0; u < 4; ++u) { kT[col+u][t0] = kv[u]; vl[t0][col+u] = vv[u]; }
    }
  }
  __syncthreads();

  const int j  = tid & 63;          // lane
  const int ig = tid >> 6;          // wave id (uniform per wave)

  // phase A: masked QK^T (q rows broadcast from global/L1, k from LDS transposed)
  for (int r = 0; r < 16; ++r) {
    const int i = r*4 + ig;
    const float* qrow = qbuf + base + (size_t)i * HS;
    float s0 = 0.f, s1 = 0.f, s2 = 0.f, s3 = 0.f;
    #pragma unroll
    for (int d = 0; d < HS; d += 4) {
      float qv[4]; *(float4*)qv = *(const float4*)&qrow[d];
      s0 += qv[0] * kT[d+0][j];
      s1 += qv[1] * kT[d+1][j];
      s2 += qv[2] * kT[d+2][j];
      s3 += qv[3] * kT[d+3][j];
    }
    Al[i][j] = (j <= i) ? ((s0+s1) + (s2+s3)) : 0.f;
  }
  __syncthreads();

  // phase B
  const int f = j;
  const float* Sp = Sc + ((size_t)h * NC + c) * (HS * HS);
  const float* Zp = Zc + ((size_t)h * NC + c) * HS;
  float num[16], den[16];

  // inter-chunk state contribution
  for (int r = 0; r < 16; ++r) {
    const int i = r*4 + ig;
    const float* qrow = qbuf + base + (size_t)i * HS;
    float n0=0.f,n1=0.f,n2=0.f,n3=0.f, e0=0.f,e1=0.f,e2=0.f,e3=0.f;
    #pragma unroll
    for (int d = 0; d < HS; d += 4) {
      float qv[4]; *(float4*)qv = *(const float4*)&qrow[d];
      n0 += qv[0] * Sp[(d+0)*HS + f];  e0 += qv[0] * Zp[d+0];
      n1 += qv[1] * Sp[(d+1)*HS + f];  e1 += qv[1] * Zp[d+1];
      n2 += qv[2] * Sp[(d+2)*HS + f];  e2 += qv[2] * Zp[d+2];
      n3 += qv[3] * Sp[(d+3)*HS + f];  e3 += qv[3] * Zp[d+3];
    }
    num[r] = (n0+n1) + (n2+n3);
    den[r] = (e0+e1) + (e2+e3);
  }

  // intra-chunk contribution (mask already baked into Al as zeros)
  for (int jj4 = 0; jj4 < 16; ++jj4) {
    float vv[4];
    #pragma unroll
    for (int u = 0; u < 4; ++u) vv[u] = vl[jj4*4 + u][f];
    #pragma unroll
    for (int r = 0; r < 16; ++r) {
      const int i = r*4 + ig;
      float a[4]; *(float4*)a = *(const float4*)&Al[i][jj4*4];
      #pragma unroll
      for (int u = 0; u < 4; ++u) { num[r] += a[u] * vv[u]; den[r] += a[u]; }
    }
  }

  #pragma unroll
  for (int r = 0; r < 16; ++r) {
    const int i = r*4 + ig;
    xo[(size_t)(c*64 + i) * 1024 + h*64 + f] = num[r] / (den[r] + 1e-6f);
  }
}

// ---------------------------------------------------------------------------
extern "C" void kernel_launch(void* const* d_in, const int* in_sizes, int n_in,
                              void* d_out, int out_size, void* d_ws, size_t ws_size,
                              hipStream_t stream)
{
  (void)in_sizes; (void)n_in; (void)out_size; (void)ws_size;
  const float* x     = (const float*)d_in[0];
  const float* w_qkv = (const float*)d_in[1];
  const float* w_out = (const float*)d_in[2];
  float* out = (float*)d_out;
  float* ws  = (float*)d_ws;

  // workspace layout (floats): total ~42.1 MB
  float* qbuf = ws;                                   // [16][2048][64] phi(q)
  float* kbuf = qbuf + QK_ELEMS;                      // [16][2048][64] phi(k)
  float* vbuf = kbuf + QK_ELEMS;                      // [16][2048][64] v
  float* Sc   = vbuf + QK_ELEMS;                      // [16][32][64][64]
  float* Zc   = Sc + (size_t)HEADS * NC * HS * HS;    // [16][32][64]
  float* xo   = Zc + (size_t)HEADS * NC * HS;         // [2048][1024]

  // 1) qkv = x @ w_qkv^T, phi on q,k, scatter to per-head layout
  gemm_nt<1><<<dim3(24, 16), 256, 0, stream>>>(x, w_qkv, nullptr, 2048, 3072, 1024, qbuf);
  // 2) per-chunk KV sums
  chunk_kv<<<dim3(16, 32), 256, 0, stream>>>(kbuf, vbuf, Sc, Zc);
  // 3) exclusive prefix over chunks
  scan_chunks<<<16, 256, 0, stream>>>(Sc, Zc);
  // 4) chunk outputs -> xo in [T][D] layout
  chunk_attn<<<dim3(16, 32), 256, 0, stream>>>(qbuf, kbuf, vbuf, Sc, Zc, xo);
  // 5) out = xo @ w_out^T
  gemm_nt<0><<<dim3(8, 16), 256, 0, stream>>>(xo, w_out, out, 2048, 1024, 1024, nullptr);
}

// Round 2
// 256.572 us; speedup vs baseline: 2.3251x; 2.3251x over previous
//
#include <hip/hip_runtime.h>
#include <cmath>

#define T_SEQ 2048
#define HEADS 16
#define HS 64
#define NC 32
#define K2 2048       // split storage: [hi plane (1024) | lo plane (1024)] bf16
#define D_MODEL 1024

typedef __attribute__((ext_vector_type(4))) float f32x4;
typedef __attribute__((ext_vector_type(8))) unsigned short u16x8;
typedef __attribute__((ext_vector_type(4))) unsigned short u16x4;

__device__ __forceinline__ unsigned short f2bf_rne(float f){
  unsigned u = __builtin_bit_cast(unsigned, f);
  return (unsigned short)((u + 0x7FFFu + ((u >> 16) & 1u)) >> 16);
}
__device__ __forceinline__ float bf2f(unsigned short h){
  unsigned u = ((unsigned)h) << 16;
  return __builtin_bit_cast(float, u);
}

// ---------------------------------------------------------------------------
// fp32 [R][1024] -> bf16 [R][2048] = [hi | lo]
// ---------------------------------------------------------------------------
__global__ __launch_bounds__(256)
void split_bf16(const float* __restrict__ src, unsigned short* __restrict__ dst, int nq)
{
  int q = blockIdx.x * 256 + threadIdx.x;
  if (q >= nq) return;
  float4 v = ((const float4*)src)[q];
  float f[4] = {v.x, v.y, v.z, v.w};
  u16x4 hi, lo;
  #pragma unroll
  for (int i = 0; i < 4; ++i){
    unsigned short h = f2bf_rne(f[i]);
    hi[i] = h;
    lo[i] = f2bf_rne(f[i] - bf2f(h));
  }
  size_t row = (size_t)(q >> 8);
  int c4 = (q & 255) * 4;
  *(u16x4*)(dst + row * K2 + c4) = hi;
  *(u16x4*)(dst + row * K2 + D_MODEL + c4) = lo;
}

// ---------------------------------------------------------------------------
// MFMA split-bf16 GEMM: C[M][N] = A[M][1024] * B[N][1024]^T  (fp32-accurate)
// virtual K=3072: steps 0..15 Ah*Bh, 16..31 Ah*Bl, 32..47 Al*Bh.
// 128xBN tile, BK=64, global_load_lds w=16, T2 XOR swizzle both-sides.
// EPI=0: plain C store. EPI=1: phi(q,k)=elu+1, scatter to [3*16][2048][64].
// ---------------------------------------------------------------------------
__device__ __forceinline__ void gload_lds16(const unsigned short* g, void* l){
  __builtin_amdgcn_global_load_lds((const __attribute__((address_space(1))) unsigned int*)g,
                                   (__attribute__((address_space(3))) unsigned int*)l,
                                   16, 0, 0);
}

__device__ __forceinline__ void mfma_bf16(f32x4& d, u16x8 a, u16x8 b){
  asm("v_mfma_f32_16x16x32_bf16 %0, %1, %2, %0" : "+v"(d) : "v"(a), "v"(b));
}

template<int BN, int EPI>
__global__ __launch_bounds__(256, 2)
void gemm_split(const unsigned short* __restrict__ A2,
                const unsigned short* __restrict__ B2,
                float* __restrict__ C, int N,
                float* __restrict__ qkvws)
{
  __shared__ unsigned char lds[16384 + BN * 128];
  unsigned char* AsB = lds;
  unsigned char* BsB = lds + 16384;
  constexpr int NI = BN / 32;     // N-fragments per wave; also B staging issues

  const int tid   = threadIdx.x;
  const int tileM = blockIdx.y * 128;
  const int tileN = blockIdx.x * BN;
  const int lane  = tid & 63;
  const int wid   = tid >> 6;
  const int wr    = (wid >> 1) * 64;
  const int wc    = (wid & 1) * (BN / 2);

  f32x4 acc[4][NI];
  #pragma unroll
  for (int i = 0; i < 4; ++i)
    #pragma unroll
    for (int j = 0; j < NI; ++j) acc[i][j] = (f32x4)0.f;

  const int srow = tid >> 3;          // 0..31 (row within a 32-row staging issue)
  const int kbp  = (tid & 7) << 4;    // physical byte offset in 128B row

  for (int kt = 0; kt < 48; ++kt) {
    int a_k, b_k;                     // element offset into the [hi|lo] K2 row
    if (kt < 16)      { a_k = kt << 6;                   b_k = kt << 6; }
    else if (kt < 32) { a_k = (kt - 16) << 6;            b_k = D_MODEL + ((kt - 16) << 6); }
    else              { a_k = D_MODEL + ((kt - 32) << 6); b_k = (kt - 32) << 6; }

    __syncthreads();
    #pragma unroll
    for (int i = 0; i < 4; ++i){      // A: 128x64 bf16 = 16KB, 4 issues
      int row = i * 32 + srow;
      int kb  = kbp ^ ((row & 7) << 4);   // inverse-swizzled SOURCE (rule 21)
      gload_lds16(A2 + (size_t)(tileM + row) * K2 + a_k + (kb >> 1),
                  AsB + i * 4096 + tid * 16);
    }
    #pragma unroll
    for (int i = 0; i < NI; ++i){     // B: BNx64 bf16
      int row = i * 32 + srow;
      int kb  = kbp ^ ((row & 7) << 4);
      gload_lds16(B2 + (size_t)(tileN + row) * K2 + b_k + (kb >> 1),
                  BsB + i * 4096 + tid * 16);
    }
    __syncthreads();

    #pragma unroll
    for (int ks = 0; ks < 2; ++ks){
      u16x8 af[4], bfr[NI];
      #pragma unroll
      for (int mi = 0; mi < 4; ++mi){
        int row = wr + mi * 16 + (lane & 15);
        int kb  = ((ks << 6) + ((lane >> 4) << 4)) ^ ((row & 7) << 4);  // swizzled read
        af[mi] = *(const u16x8*)(AsB + row * 128 + kb);
      }
      #pragma unroll
      for (int ni = 0; ni < NI; ++ni){
        int row = wc + ni * 16 + (lane & 15);
        int kb  = ((ks << 6) + ((lane >> 4) << 4)) ^ ((row & 7) << 4);
        bfr[ni] = *(const u16x8*)(BsB + row * 128 + kb);
      }
      #pragma unroll
      for (int mi = 0; mi < 4; ++mi)
        #pragma unroll
        for (int ni = 0; ni < NI; ++ni)
          mfma_bf16(acc[mi][ni], af[mi], bfr[ni]);
    }
  }

  // epilogue: C/D layout col=lane&15, row=(lane>>4)*4+reg  [m89-verified]
  const int r0 = (lane >> 4) << 2;
  const int cl = lane & 15;
  if constexpr (EPI == 0) {
    #pragma unroll
    for (int mi = 0; mi < 4; ++mi){
      int gr = tileM + wr + mi * 16 + r0;
      #pragma unroll
      for (int ni = 0; ni < NI; ++ni){
        int gc = tileN + wc + ni * 16 + cl;
        #pragma unroll
        for (int r = 0; r < 4; ++r) C[(size_t)(gr + r) * N + gc] = acc[mi][ni][r];
      }
    }
  } else {
    #pragma unroll
    for (int ni = 0; ni < NI; ++ni){
      int gc = tileN + wc + ni * 16 + cl;
      int c3 = gc >> 10;                 // 0:q 1:k 2:v
      int h  = (gc >> 6) & 15;
      int s  = gc & 63;
      float* dst = qkvws + ((size_t)(c3 * HEADS + h) * T_SEQ) * HS + s;
      #pragma unroll
      for (int mi = 0; mi < 4; ++mi){
        int gr = tileM + wr + mi * 16 + r0;
        #pragma unroll
        for (int r = 0; r < 4; ++r){
          float v = acc[mi][ni][r];
          if (c3 < 2) v = (v > 0.f) ? (v + 1.f) : expf(v);  // phi = elu+1
          dst[(size_t)(gr + r) * HS] = v;
        }
      }
    }
  }
}

// ---------------------------------------------------------------------------
// Per-chunk KV sums: S_c = sum k (x) v  [64x64],  z_c = sum k  [64]
// ---------------------------------------------------------------------------
__global__ __launch_bounds__(256)
void chunk_kv(const float* __restrict__ kbuf, const float* __restrict__ vbuf,
              float* __restrict__ Sc, float* __restrict__ Zc)
{
  const int h = blockIdx.x, c = blockIdx.y;
  const int tid = threadIdx.x;
  const int f = tid & 63, dg = tid >> 6;
  const size_t base = ((size_t)h * T_SEQ + c * 64) * HS;
  float s[16] = {};
  float z = 0.f;
  for (int t = 0; t < 64; ++t) {
    const float vv = vbuf[base + t * HS + f];
    const float* krow = kbuf + base + t * HS + dg * 16;
    float kk4[16];
    #pragma unroll
    for (int r4 = 0; r4 < 4; ++r4)
      *(float4*)&kk4[r4 * 4] = *(const float4*)&krow[r4 * 4];
    #pragma unroll
    for (int r = 0; r < 16; ++r) s[r] += kk4[r] * vv;
    if (dg == 0) z += kbuf[base + t * HS + f];
  }
  float* Sp = Sc + ((size_t)h * NC + c) * (HS * HS);
  #pragma unroll
  for (int r = 0; r < 16; ++r) Sp[(dg * 16 + r) * HS + f] = s[r];
  if (dg == 0) Zc[((size_t)h * NC + c) * HS + f] = z;
}

// ---------------------------------------------------------------------------
// Exclusive prefix over the 32 chunks. grid (16 heads, 16 e-blocks).
// ---------------------------------------------------------------------------
__global__ __launch_bounds__(256)
void scan_chunks(float* __restrict__ Sc, float* __restrict__ Zc)
{
  const int h = blockIdx.x;
  const int e = blockIdx.y * 256 + threadIdx.x;
  float* p = Sc + ((size_t)h * NC) * (HS * HS) + e;
  float run = 0.f;
  for (int c = 0; c < NC; ++c) {
    float v = p[(size_t)c * HS * HS]; p[(size_t)c * HS * HS] = run; run += v;
  }
  if (blockIdx.y == 0 && threadIdx.x < HS) {
    float* z = Zc + (size_t)h * NC * HS + threadIdx.x;
    float run2 = 0.f;
    for (int c = 0; c < NC; ++c) { float v = z[c * HS]; z[c * HS] = run2; run2 += v; }
  }
}

// ---------------------------------------------------------------------------
// Per-chunk output (intra causal + inter state), writes xo in [T][D] layout.
// ---------------------------------------------------------------------------
__global__ __launch_bounds__(256)
void chunk_attn(const float* __restrict__ qbuf, const float* __restrict__ kbuf,
                const float* __restrict__ vbuf, const float* __restrict__ Sc,
                const float* __restrict__ Zc, float* __restrict__ xo)
{
  __shared__ float kT[HS][64];
  __shared__ float vl[64][HS + 1];
  __shared__ float Al[64][64];
  const int h = blockIdx.x, c = blockIdx.y;
  const int tid = threadIdx.x;
  const size_t base = ((size_t)h * T_SEQ + c * 64) * HS;

  {
    const int t0 = tid >> 2;
    const int cq = (tid & 3) * 4;
    #pragma unroll
    for (int it = 0; it < 4; ++it) {
      const int col = cq + it * 16;
      float kv[4]; *(float4*)kv = *(const float4*)&kbuf[base + (size_t)t0 * HS + col];
      float vv[4]; *(float4*)vv = *(const float4*)&vbuf[base + (size_t)t0 * HS + col];
      #pragma unroll
      for (int u = 0; u < 4; ++u) { kT[col + u][t0] = kv[u]; vl[t0][col + u] = vv[u]; }
    }
  }
  __syncthreads();

  const int j  = tid & 63;
  const int ig = tid >> 6;

  for (int r = 0; r < 16; ++r) {
    const int i = r * 4 + ig;
    const float* qrow = qbuf + base + (size_t)i * HS;
    float s0 = 0.f, s1 = 0.f, s2 = 0.f, s3 = 0.f;
    #pragma unroll
    for (int d = 0; d < HS; d += 4) {
      float qv[4]; *(float4*)qv = *(const float4*)&qrow[d];
      s0 += qv[0] * kT[d + 0][j];
      s1 += qv[1] * kT[d + 1][j];
      s2 += qv[2] * kT[d + 2][j];
      s3 += qv[3] * kT[d + 3][j];
    }
    Al[i][j] = (j <= i) ? ((s0 + s1) + (s2 + s3)) : 0.f;
  }
  __syncthreads();

  const int f = j;
  const float* Sp = Sc + ((size_t)h * NC + c) * (HS * HS);
  const float* Zp = Zc + ((size_t)h * NC + c) * HS;
  float num[16], den[16];

  for (int r = 0; r < 16; ++r) {
    const int i = r * 4 + ig;
    const float* qrow = qbuf + base + (size_t)i * HS;
    float n0=0.f,n1=0.f,n2=0.f,n3=0.f, e0=0.f,e1=0.f,e2=0.f,e3=0.f;
    #pragma unroll
    for (int d = 0; d < HS; d += 4) {
      float qv[4]; *(float4*)qv = *(const float4*)&qrow[d];
      n0 += qv[0] * Sp[(d + 0) * HS + f];  e0 += qv[0] * Zp[d + 0];
      n1 += qv[1] * Sp[(d + 1) * HS + f];  e1 += qv[1] * Zp[d + 1];
      n2 += qv[2] * Sp[(d + 2) * HS + f];  e2 += qv[2] * Zp[d + 2];
      n3 += qv[3] * Sp[(d + 3) * HS + f];  e3 += qv[3] * Zp[d + 3];
    }
    num[r] = (n0 + n1) + (n2 + n3);
    den[r] = (e0 + e1) + (e2 + e3);
  }

  for (int jj4 = 0; jj4 < 16; ++jj4) {
    float vv[4];
    #pragma unroll
    for (int u = 0; u < 4; ++u) vv[u] = vl[jj4 * 4 + u][f];
    #pragma unroll
    for (int r = 0; r < 16; ++r) {
      const int i = r * 4 + ig;
      float a[4]; *(float4*)a = *(const float4*)&Al[i][jj4 * 4];
      #pragma unroll
      for (int u = 0; u < 4; ++u) { num[r] += a[u] * vv[u]; den[r] += a[u]; }
    }
  }

  #pragma unroll
  for (int r = 0; r < 16; ++r) {
    const int i = r * 4 + ig;
    xo[(size_t)(c * 64 + i) * 1024 + h * 64 + f] = num[r] / (den[r] + 1e-6f);
  }
}

// ---------------------------------------------------------------------------
extern "C" void kernel_launch(void* const* d_in, const int* in_sizes, int n_in,
                              void* d_out, int out_size, void* d_ws, size_t ws_size,
                              hipStream_t stream)
{
  (void)in_sizes; (void)n_in; (void)out_size; (void)ws_size;
  const float* x     = (const float*)d_in[0];
  const float* w_qkv = (const float*)d_in[1];
  const float* w_out = (const float*)d_in[2];
  float* out = (float*)d_out;
  char* wsb = (char*)d_ws;

  // phase-disjoint workspace (peak ~45 MiB):
  float* qbuf = (float*)(wsb);                                    // 8 MiB  [16][2048][64]
  float* kbuf = (float*)(wsb + ((size_t)8  << 20));               // 8 MiB
  float* vbuf = (float*)(wsb + ((size_t)16 << 20));               // 8 MiB
  unsigned short* X2  = (unsigned short*)(wsb + ((size_t)24 << 20)); // 8 MiB (gemm1 in)
  float*          Sc  = (float*)(wsb + ((size_t)24 << 20));          // 8 MiB (aliases X2, after gemm1)
  unsigned short* Wq2 = (unsigned short*)(wsb + ((size_t)32 << 20)); // 12.6 MiB (gemm1 in)
  float*          Zc  = (float*)(wsb + ((size_t)32 << 20));          // 128 KiB (aliases Wq2, after gemm1)
  float*          xo  = (float*)(wsb + ((size_t)32 << 20) + ((size_t)128 << 10)); // 8 MiB
  unsigned short* Wo2 = (unsigned short*)(wsb + ((size_t)41 << 20)); // 4.2 MiB (after gemm1)
  unsigned short* XO2 = (unsigned short*)(wsb);                      // 8 MiB (aliases qbuf, after attn)

  split_bf16<<<2048, 256, 0, stream>>>(x,     X2,  2048 * 1024 / 4);
  split_bf16<<<3072, 256, 0, stream>>>(w_qkv, Wq2, 3072 * 1024 / 4);
  // qkv = x @ w_qkv^T (+phi on q,k), scattered per-head
  gemm_split<128, 1><<<dim3(24, 16), 256, 0, stream>>>(X2, Wq2, nullptr, 3072, qbuf);
  chunk_kv<<<dim3(16, 32), 256, 0, stream>>>(kbuf, vbuf, Sc, Zc);
  scan_chunks<<<dim3(16, 16), 256, 0, stream>>>(Sc, Zc);
  chunk_attn<<<dim3(16, 32), 256, 0, stream>>>(qbuf, kbuf, vbuf, Sc, Zc, xo);
  split_bf16<<<1024, 256, 0, stream>>>(w_out, Wo2, 1024 * 1024 / 4);
  split_bf16<<<2048, 256, 0, stream>>>(xo,    XO2, 2048 * 1024 / 4);
  // out = xo @ w_out^T
  gemm_split<64, 0><<<dim3(16, 16), 256, 0, stream>>>(XO2, Wo2, out, 1024, nullptr);
}

// Round 3
// 232.123 us; speedup vs baseline: 2.5700x; 1.1053x over previous
//
#include <hip/hip_runtime.h>
#include <cmath>

#define T_SEQ 2048
#define HEADS 16
#define HS 64
#define NC 32
#define K2 2048       // split storage: [hi plane (1024) | lo plane (1024)] bf16
#define D_MODEL 1024

typedef __attribute__((ext_vector_type(4))) float f32x4;
typedef __attribute__((ext_vector_type(8))) unsigned short u16x8;
typedef __attribute__((ext_vector_type(4))) unsigned short u16x4;

__device__ __forceinline__ unsigned short f2bf_rne(float f){
  unsigned u = __builtin_bit_cast(unsigned, f);
  return (unsigned short)((u + 0x7FFFu + ((u >> 16) & 1u)) >> 16);
}
__device__ __forceinline__ float bf2f(unsigned short h){
  unsigned u = ((unsigned)h) << 16;
  return __builtin_bit_cast(float, u);
}

// ---------------------------------------------------------------------------
// One launch: split x, w_qkv, w_out  fp32 [R][1024] -> bf16 [R][2048]=[hi|lo]
// ---------------------------------------------------------------------------
__global__ __launch_bounds__(256)
void split_all(const float* __restrict__ x, const float* __restrict__ wqkv,
               const float* __restrict__ wout,
               unsigned short* __restrict__ X2, unsigned short* __restrict__ Wq2,
               unsigned short* __restrict__ Wo2)
{
  const int b = blockIdx.x;
  const float* src; unsigned short* dst; int q0;
  if (b < 2048)      { src = x;    dst = X2;  q0 = b; }
  else if (b < 5120) { src = wqkv; dst = Wq2; q0 = b - 2048; }
  else               { src = wout; dst = Wo2; q0 = b - 5120; }
  const int q = q0 * 256 + threadIdx.x;
  float4 v = ((const float4*)src)[q];
  float f[4] = {v.x, v.y, v.z, v.w};
  u16x4 hi, lo;
  #pragma unroll
  for (int i = 0; i < 4; ++i){
    unsigned short h = f2bf_rne(f[i]);
    hi[i] = h;
    lo[i] = f2bf_rne(f[i] - bf2f(h));
  }
  size_t row = (size_t)(q >> 8);
  int c4 = (q & 255) * 4;
  *(u16x4*)(dst + row * K2 + c4) = hi;
  *(u16x4*)(dst + row * K2 + D_MODEL + c4) = lo;
}

// ---------------------------------------------------------------------------
// MFMA split-bf16 GEMM, 2-phase double-buffered prefetch (catalog T3-min).
// C[M][N] = A[M][1024] * B[N][1024]^T via virtual K=3072:
//   kt 0..15 Ah*Bh, 16..31 Ah*Bl, 32..47 Al*Bh.
// 128xBN tile, BK=64, global_load_lds w=16, T2 XOR swizzle both-sides.
// EPI=0: plain C store. EPI=1: phi(q,k)=elu+1, scatter to [3*16][2048][64].
// ---------------------------------------------------------------------------
__device__ __forceinline__ void gload_lds16(const unsigned short* g, void* l){
  __builtin_amdgcn_global_load_lds((const __attribute__((address_space(1))) unsigned int*)g,
                                   (__attribute__((address_space(3))) unsigned int*)l,
                                   16, 0, 0);
}

__device__ __forceinline__ void mfma_bf16(f32x4& d, u16x8 a, u16x8 b){
  asm("v_mfma_f32_16x16x32_bf16 %0, %1, %2, %0" : "+v"(d) : "v"(a), "v"(b));
}

template<int BN, int EPI>
__global__ __launch_bounds__(256, 2)
void gemm_split(const unsigned short* __restrict__ A2,
                const unsigned short* __restrict__ B2,
                float* __restrict__ C, int N,
                float* __restrict__ qkvws)
{
  constexpr int AB  = 16384;        // 128x64 bf16 A tile
  constexpr int BB  = BN * 128;     // BNx64 bf16 B tile
  constexpr int BUF = AB + BB;
  constexpr int NI  = BN / 32;
  __shared__ unsigned char lds[2 * BUF];

  const int tid   = threadIdx.x;
  const int tileM = blockIdx.y * 128;
  const int tileN = blockIdx.x * BN;
  const int lane  = tid & 63;
  const int wid   = tid >> 6;
  const int wr    = (wid >> 1) * 64;
  const int wc    = (wid & 1) * (BN / 2);

  f32x4 acc[4][NI];
  #pragma unroll
  for (int i = 0; i < 4; ++i)
    #pragma unroll
    for (int j = 0; j < NI; ++j) acc[i][j] = (f32x4)0.f;

  // staging geometry: issue = 32 rows x 128B; row = i*32+srow, (row&7)==(srow&7)
  const int srow = tid >> 3;
  const int kbp  = (tid & 7) << 4;
  const int skb  = kbp ^ ((srow & 7) << 4);        // inverse-swizzled source col (rule 21)
  const unsigned short* Arow = A2 + (size_t)(tileM + srow) * K2 + (skb >> 1);
  const unsigned short* Brow = B2 + (size_t)(tileN + srow) * K2 + (skb >> 1);

  auto stage = [&](int kt, int pb){
    int a_k, b_k;
    if (kt < 16)      { a_k = kt << 6;                    b_k = kt << 6; }
    else if (kt < 32) { a_k = (kt - 16) << 6;             b_k = D_MODEL + ((kt - 16) << 6); }
    else              { a_k = D_MODEL + ((kt - 32) << 6); b_k = (kt - 32) << 6; }
    unsigned char* Ad = lds + pb * BUF + tid * 16;
    unsigned char* Bd = Ad + AB;
    #pragma unroll
    for (int i = 0; i < 4; ++i)
      gload_lds16(Arow + a_k + (size_t)i * 32 * K2, Ad + i * 4096);
    #pragma unroll
    for (int i = 0; i < NI; ++i)
      gload_lds16(Brow + b_k + (size_t)i * 32 * K2, Bd + i * 4096);
  };

  auto compute = [&](int pb){
    unsigned char* Ab = lds + pb * BUF;
    unsigned char* Bb = Ab + AB;
    #pragma unroll
    for (int ks = 0; ks < 2; ++ks){
      u16x8 af[4], bfr[NI];
      #pragma unroll
      for (int mi = 0; mi < 4; ++mi){
        int row = wr + mi * 16 + (lane & 15);
        int kb  = ((ks << 6) + ((lane >> 4) << 4)) ^ ((row & 7) << 4);  // swizzled read
        af[mi] = *(const u16x8*)(Ab + row * 128 + kb);
      }
      #pragma unroll
      for (int ni = 0; ni < NI; ++ni){
        int row = wc + ni * 16 + (lane & 15);
        int kb  = ((ks << 6) + ((lane >> 4) << 4)) ^ ((row & 7) << 4);
        bfr[ni] = *(const u16x8*)(Bb + row * 128 + kb);
      }
      #pragma unroll
      for (int mi = 0; mi < 4; ++mi)
        #pragma unroll
        for (int ni = 0; ni < NI; ++ni)
          mfma_bf16(acc[mi][ni], af[mi], bfr[ni]);
    }
  };

  stage(0, 0);
  __syncthreads();          // vmcnt(0) drain: tile 0 resident
  int cur = 0;
  #pragma unroll 1
  for (int kt = 0; kt < 48; ++kt){
    if (kt + 1 < 48) stage(kt + 1, cur ^ 1);   // issue next tile FIRST
    compute(cur);                              // ds_read + MFMA current tile
    __syncthreads();                           // drains vmcnt+lgkmcnt: next tile ready
    cur ^= 1;
  }

  // epilogue: C/D layout col=lane&15, row=(lane>>4)*4+reg  [m89-verified]
  const int r0 = (lane >> 4) << 2;
  const int cl = lane & 15;
  if constexpr (EPI == 0) {
    #pragma unroll
    for (int mi = 0; mi < 4; ++mi){
      int gr = tileM + wr + mi * 16 + r0;
      #pragma unroll
      for (int ni = 0; ni < NI; ++ni){
        int gc = tileN + wc + ni * 16 + cl;
        #pragma unroll
        for (int r = 0; r < 4; ++r) C[(size_t)(gr + r) * N + gc] = acc[mi][ni][r];
      }
    }
  } else {
    #pragma unroll
    for (int ni = 0; ni < NI; ++ni){
      int gc = tileN + wc + ni * 16 + cl;
      int c3 = gc >> 10;                 // 0:q 1:k 2:v
      int hh = (gc >> 6) & 15;
      int s  = gc & 63;
      float* dst = qkvws + ((size_t)(c3 * HEADS + hh) * T_SEQ) * HS + s;
      #pragma unroll
      for (int mi = 0; mi < 4; ++mi){
        int gr = tileM + wr + mi * 16 + r0;
        #pragma unroll
        for (int r = 0; r < 4; ++r){
          float v = acc[mi][ni][r];
          if (c3 < 2) v = (v > 0.f) ? (v + 1.f) : expf(v);  // phi = elu+1
          dst[(size_t)(gr + r) * HS] = v;
        }
      }
    }
  }
}

// ---------------------------------------------------------------------------
// Per-chunk KV sums: S_c = sum k (x) v  [64x64],  z_c = sum k  [64]
// ---------------------------------------------------------------------------
__global__ __launch_bounds__(256)
void chunk_kv(const float* __restrict__ kbuf, const float* __restrict__ vbuf,
              float* __restrict__ Sc, float* __restrict__ Zc)
{
  const int h = blockIdx.x, c = blockIdx.y;
  const int tid = threadIdx.x;
  const int f = tid & 63, dg = tid >> 6;
  const size_t base = ((size_t)h * T_SEQ + c * 64) * HS;
  float s[16] = {};
  float z = 0.f;
  for (int t = 0; t < 64; ++t) {
    const float vv = vbuf[base + t * HS + f];
    const float* krow = kbuf + base + t * HS + dg * 16;
    float kk4[16];
    #pragma unroll
    for (int r4 = 0; r4 < 4; ++r4)
      *(float4*)&kk4[r4 * 4] = *(const float4*)&krow[r4 * 4];
    #pragma unroll
    for (int r = 0; r < 16; ++r) s[r] += kk4[r] * vv;
    if (dg == 0) z += kbuf[base + t * HS + f];
  }
  float* Sp = Sc + ((size_t)h * NC + c) * (HS * HS);
  #pragma unroll
  for (int r = 0; r < 16; ++r) Sp[(dg * 16 + r) * HS + f] = s[r];
  if (dg == 0) Zc[((size_t)h * NC + c) * HS + f] = z;
}

// ---------------------------------------------------------------------------
// Exclusive prefix over the 32 chunks. grid (16 heads, 16 e-blocks).
// ---------------------------------------------------------------------------
__global__ __launch_bounds__(256)
void scan_chunks(float* __restrict__ Sc, float* __restrict__ Zc)
{
  const int h = blockIdx.x;
  const int e = blockIdx.y * 256 + threadIdx.x;
  float* p = Sc + ((size_t)h * NC) * (HS * HS) + e;
  float run = 0.f;
  for (int c = 0; c < NC; ++c) {
    float v = p[(size_t)c * HS * HS]; p[(size_t)c * HS * HS] = run; run += v;
  }
  if (blockIdx.y == 0 && threadIdx.x < HS) {
    float* z = Zc + (size_t)h * NC * HS + threadIdx.x;
    float run2 = 0.f;
    for (int c = 0; c < NC; ++c) { float v = z[c * HS]; z[c * HS] = run2; run2 += v; }
  }
}

// ---------------------------------------------------------------------------
// Per-chunk output (intra causal + inter state); writes split-bf16 XO2
// directly in [T][hi|lo] layout (gemm2's A operand) — no fp32 xo round-trip.
// ---------------------------------------------------------------------------
__global__ __launch_bounds__(256)
void chunk_attn(const float* __restrict__ qbuf, const float* __restrict__ kbuf,
                const float* __restrict__ vbuf, const float* __restrict__ Sc,
                const float* __restrict__ Zc, unsigned short* __restrict__ XO2)
{
  __shared__ float kT[HS][64];
  __shared__ float vl[64][HS + 1];
  __shared__ float Al[64][64];
  const int h = blockIdx.x, c = blockIdx.y;
  const int tid = threadIdx.x;
  const size_t base = ((size_t)h * T_SEQ + c * 64) * HS;

  {
    const int t0 = tid >> 2;
    const int cq = (tid & 3) * 4;
    #pragma unroll
    for (int it = 0; it < 4; ++it) {
      const int col = cq + it * 16;
      float kv[4]; *(float4*)kv = *(const float4*)&kbuf[base + (size_t)t0 * HS + col];
      float vv[4]; *(float4*)vv = *(const float4*)&vbuf[base + (size_t)t0 * HS + col];
      #pragma unroll
      for (int u = 0; u < 4; ++u) { kT[col + u][t0] = kv[u]; vl[t0][col + u] = vv[u]; }
    }
  }
  __syncthreads();

  const int j  = tid & 63;
  const int ig = tid >> 6;

  for (int r = 0; r < 16; ++r) {
    const int i = r * 4 + ig;
    const float* qrow = qbuf + base + (size_t)i * HS;
    float s0 = 0.f, s1 = 0.f, s2 = 0.f, s3 = 0.f;
    #pragma unroll
    for (int d = 0; d < HS; d += 4) {
      float qv[4]; *(float4*)qv = *(const float4*)&qrow[d];
      s0 += qv[0] * kT[d + 0][j];
      s1 += qv[1] * kT[d + 1][j];
      s2 += qv[2] * kT[d + 2][j];
      s3 += qv[3] * kT[d + 3][j];
    }
    Al[i][j] = (j <= i) ? ((s0 + s1) + (s2 + s3)) : 0.f;
  }
  __syncthreads();

  const int f = j;
  const float* Sp = Sc + ((size_t)h * NC + c) * (HS * HS);
  const float* Zp = Zc + ((size_t)h * NC + c) * HS;
  float num[16], den[16];

  for (int r = 0; r < 16; ++r) {
    const int i = r * 4 + ig;
    const float* qrow = qbuf + base + (size_t)i * HS;
    float n0=0.f,n1=0.f,n2=0.f,n3=0.f, e0=0.f,e1=0.f,e2=0.f,e3=0.f;
    #pragma unroll
    for (int d = 0; d < HS; d += 4) {
      float qv[4]; *(float4*)qv = *(const float4*)&qrow[d];
      n0 += qv[0] * Sp[(d + 0) * HS + f];  e0 += qv[0] * Zp[d + 0];
      n1 += qv[1] * Sp[(d + 1) * HS + f];  e1 += qv[1] * Zp[d + 1];
      n2 += qv[2] * Sp[(d + 2) * HS + f];  e2 += qv[2] * Zp[d + 2];
      n3 += qv[3] * Sp[(d + 3) * HS + f];  e3 += qv[3] * Zp[d + 3];
    }
    num[r] = (n0 + n1) + (n2 + n3);
    den[r] = (e0 + e1) + (e2 + e3);
  }

  for (int jj4 = 0; jj4 < 16; ++jj4) {
    float vv[4];
    #pragma unroll
    for (int u = 0; u < 4; ++u) vv[u] = vl[jj4 * 4 + u][f];
    #pragma unroll
    for (int r = 0; r < 16; ++r) {
      const int i = r * 4 + ig;
      float a[4]; *(float4*)a = *(const float4*)&Al[i][jj4 * 4];
      #pragma unroll
      for (int u = 0; u < 4; ++u) { num[r] += a[u] * vv[u]; den[r] += a[u]; }
    }
  }

  #pragma unroll
  for (int r = 0; r < 16; ++r) {
    const int i = r * 4 + ig;
    float val = num[r] / (den[r] + 1e-6f);
    unsigned short hb = f2bf_rne(val);
    unsigned short lb = f2bf_rne(val - bf2f(hb));
    size_t rowoff = (size_t)(c * 64 + i) * K2 + h * 64 + f;
    XO2[rowoff] = hb;
    XO2[rowoff + D_MODEL] = lb;
  }
}

// ---------------------------------------------------------------------------
extern "C" void kernel_launch(void* const* d_in, const int* in_sizes, int n_in,
                              void* d_out, int out_size, void* d_ws, size_t ws_size,
                              hipStream_t stream)
{
  (void)in_sizes; (void)n_in; (void)out_size; (void)ws_size;
  const float* x     = (const float*)d_in[0];
  const float* w_qkv = (const float*)d_in[1];
  const float* w_out = (const float*)d_in[2];
  float* out = (float*)d_out;
  char* wsb = (char*)d_ws;

  // workspace (48 MiB peak), phase-disjoint aliasing:
  float* qbuf = (float*)(wsb);                                       // [0,8)   MiB
  float* kbuf = (float*)(wsb + ((size_t)8  << 20));                  // [8,16)
  float* vbuf = (float*)(wsb + ((size_t)16 << 20));                  // [16,24)
  unsigned short* X2  = (unsigned short*)(wsb + ((size_t)24 << 20)); // [24,32) gemm1 in
  float*          Sc  = (float*)(wsb + ((size_t)24 << 20));          // [24,32) after g1
  unsigned short* Wq2 = (unsigned short*)(wsb + ((size_t)32 << 20)); // [32,44) gemm1 in
  float*          Zc  = (float*)(wsb + ((size_t)32 << 20));          // [32,32.125) after g1
  unsigned short* XO2 = (unsigned short*)(wsb + ((size_t)33 << 20)); // [33,41) after g1
  unsigned short* Wo2 = (unsigned short*)(wsb + ((size_t)44 << 20)); // [44,48)

  split_all<<<6144, 256, 0, stream>>>(x, w_qkv, w_out, X2, Wq2, Wo2);
  // qkv = x @ w_qkv^T (+phi on q,k), scattered per-head
  gemm_split<128, 1><<<dim3(24, 16), 256, 0, stream>>>(X2, Wq2, nullptr, 3072, qbuf);
  chunk_kv<<<dim3(16, 32), 256, 0, stream>>>(kbuf, vbuf, Sc, Zc);
  scan_chunks<<<dim3(16, 16), 256, 0, stream>>>(Sc, Zc);
  chunk_attn<<<dim3(16, 32), 256, 0, stream>>>(qbuf, kbuf, vbuf, Sc, Zc, XO2);
  // out = xo @ w_out^T
  gemm_split<64, 0><<<dim3(16, 16), 256, 0, stream>>>(XO2, Wo2, out, 1024, nullptr);
}

// Round 8
// 217.669 us; speedup vs baseline: 2.7407x; 1.0664x over previous
//
#include <hip/hip_runtime.h>
#include <cmath>

#define T_SEQ 2048
#define HEADS 16
#define HS 64
#define NC 32
#define K2 2048       // split storage: [hi plane (1024) | lo plane (1024)] bf16
#define D_MODEL 1024

typedef __attribute__((ext_vector_type(4))) float f32x4;
typedef __attribute__((ext_vector_type(8))) unsigned short u16x8;
typedef __attribute__((ext_vector_type(4))) unsigned short u16x4;

__device__ __forceinline__ unsigned short f2bf_rne(float f){
  unsigned u = __builtin_bit_cast(unsigned, f);
  return (unsigned short)((u + 0x7FFFu + ((u >> 16) & 1u)) >> 16);
}
__device__ __forceinline__ float bf2f(unsigned short h){
  unsigned u = ((unsigned)h) << 16;
  return __builtin_bit_cast(float, u);
}

// ---------------------------------------------------------------------------
// One launch: split x, w_qkv, w_out  fp32 [R][1024] -> bf16 [R][2048]=[hi|lo]
// ---------------------------------------------------------------------------
__global__ __launch_bounds__(256)
void split_all(const float* __restrict__ x, const float* __restrict__ wqkv,
               const float* __restrict__ wout,
               unsigned short* __restrict__ X2, unsigned short* __restrict__ Wq2,
               unsigned short* __restrict__ Wo2)
{
  const int b = blockIdx.x;
  const float* src; unsigned short* dst; int q0;
  if (b < 2048)      { src = x;    dst = X2;  q0 = b; }
  else if (b < 5120) { src = wqkv; dst = Wq2; q0 = b - 2048; }
  else               { src = wout; dst = Wo2; q0 = b - 5120; }
  const int q = q0 * 256 + threadIdx.x;
  float4 v = ((const float4*)src)[q];
  float f[4] = {v.x, v.y, v.z, v.w};
  u16x4 hi, lo;
  #pragma unroll
  for (int i = 0; i < 4; ++i){
    unsigned short h = f2bf_rne(f[i]);
    hi[i] = h;
    lo[i] = f2bf_rne(f[i] - bf2f(h));
  }
  size_t row = (size_t)(q >> 8);
  int c4 = (q & 255) * 4;
  *(u16x4*)(dst + row * K2 + c4) = hi;
  *(u16x4*)(dst + row * K2 + D_MODEL + c4) = lo;
}

// ---------------------------------------------------------------------------
// MFMA split-bf16 GEMM, PHYSICAL-K schedule: per K-step (BK=64, 16 steps)
// stage {Ah,Al,Bh,Bl} once, compute all 3 plane products:
//   acc += Ah*Bh + Ah*Bl + Al*Bh      (lo*lo dropped, ~2^-18 rel)
// Tile BM x 128. Single LDS buffer; overlap comes from 2-3 blocks/CU (m114).
// XCD-aware bijective swizzle: each XCD owns an N-band (B L2-resident).
// EPI=0: plain C store (BM=64). EPI=1: phi+scatter to per-head (BM=128).
// ---------------------------------------------------------------------------
__device__ __forceinline__ void gload_lds16(const unsigned short* g, void* l){
  __builtin_amdgcn_global_load_lds((const __attribute__((address_space(1))) unsigned int*)g,
                                   (__attribute__((address_space(3))) unsigned int*)l,
                                   16, 0, 0);
}

__device__ __forceinline__ void mfma_bf16(f32x4& d, u16x8 a, u16x8 b){
  asm("v_mfma_f32_16x16x32_bf16 %0, %1, %2, %0" : "+v"(d) : "v"(a), "v"(b));
}

template<int BM, int EPI>
__global__ __launch_bounds__(256, (BM == 128) ? 2 : 3)
void gemm_split3(const unsigned short* __restrict__ A2,
                 const unsigned short* __restrict__ B2,
                 float* __restrict__ C, int N,
                 float* __restrict__ qkvws)
{
  constexpr int AT = BM * 128;          // one A plane tile (BM x 64 bf16)
  constexpr int MI = BM / 32;           // M fragments per wave
  __shared__ unsigned char lds[2 * AT + 32768];   // [Ah][Al][Bh][Bl]

  // bijective XCD swizzle (nwg % 8 == 0 in both configs)
  const int bid = blockIdx.x;
  int bx, by;
  if constexpr (EPI == 1) {             // nwg=384: XCD owns 3 bx x 16 by
    int swz = (bid & 7) * 48 + (bid >> 3);
    bx = swz >> 4; by = swz & 15;
  } else {                              // nwg=256: XCD owns 1 bx x 32 by
    int swz = (bid & 7) * 32 + (bid >> 3);
    bx = swz >> 5; by = swz & 31;
  }
  const int tileM = by * BM;
  const int tileN = bx * 128;

  const int tid  = threadIdx.x;
  const int lane = tid & 63;
  const int wid  = tid >> 6;
  const int wr   = (wid >> 1) * (BM / 2);
  const int wc   = (wid & 1) * 64;

  f32x4 acc[MI][4];
  #pragma unroll
  for (int i = 0; i < MI; ++i)
    #pragma unroll
    for (int j = 0; j < 4; ++j) acc[i][j] = (f32x4)0.f;

  // staging geometry: each issue = 32 rows x 128B; row = i*32+srow
  const int srow = tid >> 3;
  const int kbp  = (tid & 7) << 4;
  const int skb  = kbp ^ ((srow & 7) << 4);      // inverse-swizzled source (rule 21)
  const unsigned short* Arow = A2 + (size_t)(tileM + srow) * K2 + (skb >> 1);
  const unsigned short* Brow = B2 + (size_t)(tileN + srow) * K2 + (skb >> 1);
  unsigned char* dA = lds + tid * 16;

  #pragma unroll 1
  for (int kt = 0; kt < 16; ++kt){
    const int a_k = kt << 6;
    __syncthreads();                    // prev compute done -> safe to overwrite
    #pragma unroll
    for (int i = 0; i < MI; ++i){       // Ah, Al
      gload_lds16(Arow + a_k + (size_t)i * 32 * K2,           dA + i * 4096);
      gload_lds16(Arow + D_MODEL + a_k + (size_t)i * 32 * K2, dA + AT + i * 4096);
    }
    #pragma unroll
    for (int i = 0; i < 4; ++i){        // Bh, Bl
      gload_lds16(Brow + a_k + (size_t)i * 32 * K2,           dA + 2 * AT + i * 4096);
      gload_lds16(Brow + D_MODEL + a_k + (size_t)i * 32 * K2, dA + 2 * AT + 16384 + i * 4096);
    }
    __syncthreads();                    // drain: all 4 tiles resident

    #pragma unroll
    for (int ks = 0; ks < 2; ++ks){
      u16x8 ah[MI], al[MI], bh[4], bl[4];
      #pragma unroll
      for (int mi = 0; mi < MI; ++mi){
        int row = wr + mi * 16 + (lane & 15);
        int kb  = ((ks << 6) + ((lane >> 4) << 4)) ^ ((row & 7) << 4);
        ah[mi] = *(const u16x8*)(lds + row * 128 + kb);
        al[mi] = *(const u16x8*)(lds + AT + row * 128 + kb);
      }
      #pragma unroll
      for (int ni = 0; ni < 4; ++ni){
        int row = wc + ni * 16 + (lane & 15);
        int kb  = ((ks << 6) + ((lane >> 4) << 4)) ^ ((row & 7) << 4);
        bh[ni] = *(const u16x8*)(lds + 2 * AT + row * 128 + kb);
        bl[ni] = *(const u16x8*)(lds + 2 * AT + 16384 + row * 128 + kb);
      }
      #pragma unroll
      for (int mi = 0; mi < MI; ++mi)
        #pragma unroll
        for (int ni = 0; ni < 4; ++ni){
          mfma_bf16(acc[mi][ni], ah[mi], bh[ni]);   // hi*hi
          mfma_bf16(acc[mi][ni], ah[mi], bl[ni]);   // hi*lo
          mfma_bf16(acc[mi][ni], al[mi], bh[ni]);   // lo*hi
        }
    }
  }

  // epilogue: C/D layout col=lane&15, row=(lane>>4)*4+reg  [m89-verified]
  const int r0 = (lane >> 4) << 2;
  const int cl = lane & 15;
  if constexpr (EPI == 0) {
    #pragma unroll
    for (int mi = 0; mi < MI; ++mi){
      int gr = tileM + wr + mi * 16 + r0;
      #pragma unroll
      for (int ni = 0; ni < 4; ++ni){
        int gc = tileN + wc + ni * 16 + cl;
        #pragma unroll
        for (int r = 0; r < 4; ++r) C[(size_t)(gr + r) * N + gc] = acc[mi][ni][r];
      }
    }
  } else {
    #pragma unroll
    for (int ni = 0; ni < 4; ++ni){
      int gc = tileN + wc + ni * 16 + cl;
      int c3 = gc >> 10;                 // 0:q 1:k 2:v
      int hh = (gc >> 6) & 15;
      int s  = gc & 63;
      float* dst = qkvws + ((size_t)(c3 * HEADS + hh) * T_SEQ) * HS + s;
      #pragma unroll
      for (int mi = 0; mi < MI; ++mi){
        int gr = tileM + wr + mi * 16 + r0;
        #pragma unroll
        for (int r = 0; r < 4; ++r){
          float v = acc[mi][ni][r];
          if (c3 < 2) v = (v > 0.f) ? (v + 1.f) : expf(v);  // phi = elu+1
          dst[(size_t)(gr + r) * HS] = v;
        }
      }
    }
  }
}

// ---------------------------------------------------------------------------
// Per-chunk KV sums: S_c = sum k (x) v  [64x64],  z_c = sum k  [64]
// ---------------------------------------------------------------------------
__global__ __launch_bounds__(256)
void chunk_kv(const float* __restrict__ kbuf, const float* __restrict__ vbuf,
              float* __restrict__ Sc, float* __restrict__ Zc)
{
  const int h = blockIdx.x, c = blockIdx.y;
  const int tid = threadIdx.x;
  const int f = tid & 63, dg = tid >> 6;
  const size_t base = ((size_t)h * T_SEQ + c * 64) * HS;
  float s[16] = {};
  float z = 0.f;
  for (int t = 0; t < 64; ++t) {
    const float vv = vbuf[base + t * HS + f];
    const float* krow = kbuf + base + t * HS + dg * 16;
    float kk4[16];
    #pragma unroll
    for (int r4 = 0; r4 < 4; ++r4)
      *(float4*)&kk4[r4 * 4] = *(const float4*)&krow[r4 * 4];
    #pragma unroll
    for (int r = 0; r < 16; ++r) s[r] += kk4[r] * vv;
    if (dg == 0) z += kbuf[base + t * HS + f];
  }
  float* Sp = Sc + ((size_t)h * NC + c) * (HS * HS);
  #pragma unroll
  for (int r = 0; r < 16; ++r) Sp[(dg * 16 + r) * HS + f] = s[r];
  if (dg == 0) Zc[((size_t)h * NC + c) * HS + f] = z;
}

// ---------------------------------------------------------------------------
// Exclusive prefix over the 32 chunks. grid (16 heads, 16 e-blocks).
// ---------------------------------------------------------------------------
__global__ __launch_bounds__(256)
void scan_chunks(float* __restrict__ Sc, float* __restrict__ Zc)
{
  const int h = blockIdx.x;
  const int e = blockIdx.y * 256 + threadIdx.x;
  float* p = Sc + ((size_t)h * NC) * (HS * HS) + e;
  float run = 0.f;
  for (int c = 0; c < NC; ++c) {
    float v = p[(size_t)c * HS * HS]; p[(size_t)c * HS * HS] = run; run += v;
  }
  if (blockIdx.y == 0 && threadIdx.x < HS) {
    float* z = Zc + (size_t)h * NC * HS + threadIdx.x;
    float run2 = 0.f;
    for (int c = 0; c < NC; ++c) { float v = z[c * HS]; z[c * HS] = run2; run2 += v; }
  }
}

// ---------------------------------------------------------------------------
// Per-chunk output (intra causal + inter state); writes split-bf16 XO2
// directly in [T][hi|lo] layout (gemm2's A operand) — no fp32 xo round-trip.
// ---------------------------------------------------------------------------
__global__ __launch_bounds__(256)
void chunk_attn(const float* __restrict__ qbuf, const float* __restrict__ kbuf,
                const float* __restrict__ vbuf, const float* __restrict__ Sc,
                const float* __restrict__ Zc, unsigned short* __restrict__ XO2)
{
  __shared__ float kT[HS][64];
  __shared__ float vl[64][HS + 1];
  __shared__ float Al[64][64];
  const int h = blockIdx.x, c = blockIdx.y;
  const int tid = threadIdx.x;
  const size_t base = ((size_t)h * T_SEQ + c * 64) * HS;

  {
    const int t0 = tid >> 2;
    const int cq = (tid & 3) * 4;
    #pragma unroll
    for (int it = 0; it < 4; ++it) {
      const int col = cq + it * 16;
      float kv[4]; *(float4*)kv = *(const float4*)&kbuf[base + (size_t)t0 * HS + col];
      float vv[4]; *(float4*)vv = *(const float4*)&vbuf[base + (size_t)t0 * HS + col];
      #pragma unroll
      for (int u = 0; u < 4; ++u) { kT[col + u][t0] = kv[u]; vl[t0][col + u] = vv[u]; }
    }
  }
  __syncthreads();

  const int j  = tid & 63;
  const int ig = tid >> 6;

  for (int r = 0; r < 16; ++r) {
    const int i = r * 4 + ig;
    const float* qrow = qbuf + base + (size_t)i * HS;
    float s0 = 0.f, s1 = 0.f, s2 = 0.f, s3 = 0.f;
    #pragma unroll
    for (int d = 0; d < HS; d += 4) {
      float qv[4]; *(float4*)qv = *(const float4*)&qrow[d];
      s0 += qv[0] * kT[d + 0][j];
      s1 += qv[1] * kT[d + 1][j];
      s2 += qv[2] * kT[d + 2][j];
      s3 += qv[3] * kT[d + 3][j];
    }
    Al[i][j] = (j <= i) ? ((s0 + s1) + (s2 + s3)) : 0.f;
  }
  __syncthreads();

  const int f = j;
  const float* Sp = Sc + ((size_t)h * NC + c) * (HS * HS);
  const float* Zp = Zc + ((size_t)h * NC + c) * HS;
  float num[16], den[16];

  for (int r = 0; r < 16; ++r) {
    const int i = r * 4 + ig;
    const float* qrow = qbuf + base + (size_t)i * HS;
    float n0=0.f,n1=0.f,n2=0.f,n3=0.f, e0=0.f,e1=0.f,e2=0.f,e3=0.f;
    #pragma unroll
    for (int d = 0; d < HS; d += 4) {
      float qv[4]; *(float4*)qv = *(const float4*)&qrow[d];
      n0 += qv[0] * Sp[(d + 0) * HS + f];  e0 += qv[0] * Zp[d + 0];
      n1 += qv[1] * Sp[(d + 1) * HS + f];  e1 += qv[1] * Zp[d + 1];
      n2 += qv[2] * Sp[(d + 2) * HS + f];  e2 += qv[2] * Zp[d + 2];
      n3 += qv[3] * Sp[(d + 3) * HS + f];  e3 += qv[3] * Zp[d + 3];
    }
    num[r] = (n0 + n1) + (n2 + n3);
    den[r] = (e0 + e1) + (e2 + e3);
  }

  for (int jj4 = 0; jj4 < 16; ++jj4) {
    float vv[4];
    #pragma unroll
    for (int u = 0; u < 4; ++u) vv[u] = vl[jj4 * 4 + u][f];
    #pragma unroll
    for (int r = 0; r < 16; ++r) {
      const int i = r * 4 + ig;
      float a[4]; *(float4*)a = *(const float4*)&Al[i][jj4 * 4];
      #pragma unroll
      for (int u = 0; u < 4; ++u) { num[r] += a[u] * vv[u]; den[r] += a[u]; }
    }
  }

  #pragma unroll
  for (int r = 0; r < 16; ++r) {
    const int i = r * 4 + ig;
    float val = num[r] / (den[r] + 1e-6f);
    unsigned short hb = f2bf_rne(val);
    unsigned short lb = f2bf_rne(val - bf2f(hb));
    size_t rowoff = (size_t)(c * 64 + i) * K2 + h * 64 + f;
    XO2[rowoff] = hb;
    XO2[rowoff + D_MODEL] = lb;
  }
}

// ---------------------------------------------------------------------------
extern "C" void kernel_launch(void* const* d_in, const int* in_sizes, int n_in,
                              void* d_out, int out_size, void* d_ws, size_t ws_size,
                              hipStream_t stream)
{
  (void)in_sizes; (void)n_in; (void)out_size; (void)ws_size;
  const float* x     = (const float*)d_in[0];
  const float* w_qkv = (const float*)d_in[1];
  const float* w_out = (const float*)d_in[2];
  float* out = (float*)d_out;
  char* wsb = (char*)d_ws;

  // workspace (48 MiB peak), phase-disjoint aliasing:
  float* qbuf = (float*)(wsb);                                       // [0,8)   MiB
  float* kbuf = (float*)(wsb + ((size_t)8  << 20));                  // [8,16)
  float* vbuf = (float*)(wsb + ((size_t)16 << 20));                  // [16,24)
  unsigned short* X2  = (unsigned short*)(wsb + ((size_t)24 << 20)); // [24,32) gemm1 in
  float*          Sc  = (float*)(wsb + ((size_t)24 << 20));          // [24,32) after g1
  unsigned short* Wq2 = (unsigned short*)(wsb + ((size_t)32 << 20)); // [32,44) gemm1 in
  float*          Zc  = (float*)(wsb + ((size_t)32 << 20));          // [32,32.125) after g1
  unsigned short* XO2 = (unsigned short*)(wsb + ((size_t)33 << 20)); // [33,41) after g1
  unsigned short* Wo2 = (unsigned short*)(wsb + ((size_t)44 << 20)); // [44,48)

  split_all<<<6144, 256, 0, stream>>>(x, w_qkv, w_out, X2, Wq2, Wo2);
  // qkv = x @ w_qkv^T (+phi on q,k), scattered per-head. 384 blocks (16Mx24N)
  gemm_split3<128, 1><<<384, 256, 0, stream>>>(X2, Wq2, nullptr, 3072, qbuf);
  chunk_kv<<<dim3(16, 32), 256, 0, stream>>>(kbuf, vbuf, Sc, Zc);
  scan_chunks<<<dim3(16, 16), 256, 0, stream>>>(Sc, Zc);
  chunk_attn<<<dim3(16, 32), 256, 0, stream>>>(qbuf, kbuf, vbuf, Sc, Zc, XO2);
  // out = xo @ w_out^T. 256 blocks (32Mx8N), 64x128 tile
  gemm_split3<64, 0><<<256, 256, 0, stream>>>(XO2, Wo2, out, 1024, nullptr);
}

// Round 9
// 183.548 us; speedup vs baseline: 3.2502x; 1.1859x over previous
//
#include <hip/hip_runtime.h>
#include <cmath>

#define T_SEQ 2048
#define HEADS 16
#define HS 64
#define NC 32
#define K2 2048       // split storage: [hi plane (1024) | lo plane (1024)] bf16
#define D_MODEL 1024

typedef __attribute__((ext_vector_type(4))) float f32x4;
typedef __attribute__((ext_vector_type(8))) unsigned short u16x8;
typedef __attribute__((ext_vector_type(4))) unsigned short u16x4;

__device__ __forceinline__ unsigned short f2bf_rne(float f){
  unsigned u = __builtin_bit_cast(unsigned, f);
  return (unsigned short)((u + 0x7FFFu + ((u >> 16) & 1u)) >> 16);
}
__device__ __forceinline__ float bf2f(unsigned short h){
  unsigned u = ((unsigned)h) << 16;
  return __builtin_bit_cast(float, u);
}

// ---------------------------------------------------------------------------
// split x, w_qkv, w_out -> [hi|lo] bf16 rows; blocks >= 6144 fill VT2 rows
// 64..79 (row 64 = ones-hi for the den column, 65..79 = 0).
// ---------------------------------------------------------------------------
__global__ __launch_bounds__(256)
void split_all(const float* __restrict__ x, const float* __restrict__ wqkv,
               const float* __restrict__ wout,
               unsigned short* __restrict__ X2, unsigned short* __restrict__ Wq2,
               unsigned short* __restrict__ Wo2, unsigned short* __restrict__ VT2)
{
  const int b = blockIdx.x;
  if (b >= 6144) {            // VT2 special-row fill: [16][16][2][2048] u16
    int g   = (b - 6144) * 2048 + threadIdx.x * 8;
    int hh  = g >> 16;
    int rem = g & 65535;
    int fi  = rem >> 12;      // 0..15 -> f = 64+fi
    int pl  = (rem >> 11) & 1;
    int t   = rem & 2047;
    u16x8 val;
    unsigned short fill = (fi == 0 && pl == 0) ? (unsigned short)0x3F80 : (unsigned short)0;
    #pragma unroll
    for (int e = 0; e < 8; ++e) val[e] = fill;
    *(u16x8*)(VT2 + ((size_t)((hh * 80 + 64 + fi) * 2 + pl)) * 2048 + t) = val;
    return;
  }
  const float* src; unsigned short* dst; int q0;
  if (b < 2048)      { src = x;    dst = X2;  q0 = b; }
  else if (b < 5120) { src = wqkv; dst = Wq2; q0 = b - 2048; }
  else               { src = wout; dst = Wo2; q0 = b - 5120; }
  const int q = q0 * 256 + threadIdx.x;
  float4 v = ((const float4*)src)[q];
  float f[4] = {v.x, v.y, v.z, v.w};
  u16x4 hi, lo;
  #pragma unroll
  for (int i = 0; i < 4; ++i){
    unsigned short h = f2bf_rne(f[i]);
    hi[i] = h;
    lo[i] = f2bf_rne(f[i] - bf2f(h));
  }
  size_t row = (size_t)(q >> 8);
  int c4 = (q & 255) * 4;
  *(u16x4*)(dst + row * K2 + c4) = hi;
  *(u16x4*)(dst + row * K2 + D_MODEL + c4) = lo;
}

// ---------------------------------------------------------------------------
// MFMA split-bf16 GEMM (physical-K, verified r8). EPI=0: plain C store.
// EPI=1: phi on q,k; writes bf16 operand layouts for the MFMA mid-chain:
//   Q2/K2k [h][t][d_hi64|d_lo64], kT2 [h][d][pl][t], VT2 [h][f][pl][t].
// ---------------------------------------------------------------------------
__device__ __forceinline__ void gload_lds16(const unsigned short* g, void* l){
  __builtin_amdgcn_global_load_lds((const __attribute__((address_space(1))) unsigned int*)g,
                                   (__attribute__((address_space(3))) unsigned int*)l,
                                   16, 0, 0);
}

__device__ __forceinline__ void mfma_bf16(f32x4& d, u16x8 a, u16x8 b){
  asm("v_mfma_f32_16x16x32_bf16 %0, %1, %2, %0" : "+v"(d) : "v"(a), "v"(b));
}

template<int BM, int EPI>
__global__ __launch_bounds__(256, (BM == 128) ? 2 : 3)
void gemm_split3(const unsigned short* __restrict__ A2,
                 const unsigned short* __restrict__ B2,
                 float* __restrict__ C, int N,
                 unsigned short* __restrict__ Q2, unsigned short* __restrict__ K2k,
                 unsigned short* __restrict__ kT2, unsigned short* __restrict__ VT2)
{
  constexpr int AT = BM * 128;
  constexpr int MI = BM / 32;
  __shared__ unsigned char lds[2 * AT + 32768];   // [Ah][Al][Bh][Bl]

  const int bid = blockIdx.x;
  int bx, by;
  if constexpr (EPI == 1) {             // nwg=384: XCD owns 3 bx x 16 by
    int swz = (bid & 7) * 48 + (bid >> 3);
    bx = swz >> 4; by = swz & 15;
  } else {                              // nwg=256: XCD owns 1 bx x 32 by
    int swz = (bid & 7) * 32 + (bid >> 3);
    bx = swz >> 5; by = swz & 31;
  }
  const int tileM = by * BM;
  const int tileN = bx * 128;

  const int tid  = threadIdx.x;
  const int lane = tid & 63;
  const int wid  = tid >> 6;
  const int wr   = (wid >> 1) * (BM / 2);
  const int wc   = (wid & 1) * 64;

  f32x4 acc[MI][4];
  #pragma unroll
  for (int i = 0; i < MI; ++i)
    #pragma unroll
    for (int j = 0; j < 4; ++j) acc[i][j] = (f32x4)0.f;

  const int srow = tid >> 3;
  const int kbp  = (tid & 7) << 4;
  const int skb  = kbp ^ ((srow & 7) << 4);      // inverse-swizzled source (rule 21)
  const unsigned short* Arow = A2 + (size_t)(tileM + srow) * K2 + (skb >> 1);
  const unsigned short* Brow = B2 + (size_t)(tileN + srow) * K2 + (skb >> 1);
  unsigned char* dA = lds + tid * 16;

  #pragma unroll 1
  for (int kt = 0; kt < 16; ++kt){
    const int a_k = kt << 6;
    __syncthreads();
    #pragma unroll
    for (int i = 0; i < MI; ++i){       // Ah, Al
      gload_lds16(Arow + a_k + (size_t)i * 32 * K2,           dA + i * 4096);
      gload_lds16(Arow + D_MODEL + a_k + (size_t)i * 32 * K2, dA + AT + i * 4096);
    }
    #pragma unroll
    for (int i = 0; i < 4; ++i){        // Bh, Bl
      gload_lds16(Brow + a_k + (size_t)i * 32 * K2,           dA + 2 * AT + i * 4096);
      gload_lds16(Brow + D_MODEL + a_k + (size_t)i * 32 * K2, dA + 2 * AT + 16384 + i * 4096);
    }
    __syncthreads();

    #pragma unroll
    for (int ks = 0; ks < 2; ++ks){
      u16x8 ah[MI], al[MI], bh[4], bl[4];
      #pragma unroll
      for (int mi = 0; mi < MI; ++mi){
        int row = wr + mi * 16 + (lane & 15);
        int kb  = ((ks << 6) + ((lane >> 4) << 4)) ^ ((row & 7) << 4);
        ah[mi] = *(const u16x8*)(lds + row * 128 + kb);
        al[mi] = *(const u16x8*)(lds + AT + row * 128 + kb);
      }
      #pragma unroll
      for (int ni = 0; ni < 4; ++ni){
        int row = wc + ni * 16 + (lane & 15);
        int kb  = ((ks << 6) + ((lane >> 4) << 4)) ^ ((row & 7) << 4);
        bh[ni] = *(const u16x8*)(lds + 2 * AT + row * 128 + kb);
        bl[ni] = *(const u16x8*)(lds + 2 * AT + 16384 + row * 128 + kb);
      }
      #pragma unroll
      for (int mi = 0; mi < MI; ++mi)
        #pragma unroll
        for (int ni = 0; ni < 4; ++ni){
          mfma_bf16(acc[mi][ni], ah[mi], bh[ni]);
          mfma_bf16(acc[mi][ni], ah[mi], bl[ni]);
          mfma_bf16(acc[mi][ni], al[mi], bh[ni]);
        }
    }
  }

  const int r0 = (lane >> 4) << 2;
  const int cl = lane & 15;
  if constexpr (EPI == 0) {
    #pragma unroll
    for (int mi = 0; mi < MI; ++mi){
      int gr = tileM + wr + mi * 16 + r0;
      #pragma unroll
      for (int ni = 0; ni < 4; ++ni){
        int gc = tileN + wc + ni * 16 + cl;
        #pragma unroll
        for (int r = 0; r < 4; ++r) C[(size_t)(gr + r) * N + gc] = acc[mi][ni][r];
      }
    }
  } else {
    #pragma unroll
    for (int ni = 0; ni < 4; ++ni){
      int gc = tileN + wc + ni * 16 + cl;
      int c3 = gc >> 10;                 // 0:q 1:k 2:v
      int hh = (gc >> 6) & 15;
      int s  = gc & 63;
      #pragma unroll
      for (int mi = 0; mi < MI; ++mi){
        int gr0 = tileM + wr + mi * 16 + r0;   // 4 consecutive t
        u16x4 h4, l4;
        #pragma unroll
        for (int r = 0; r < 4; ++r){
          float v = acc[mi][ni][r];
          if (c3 < 2) v = (v > 0.f) ? (v + 1.f) : expf(v);  // phi = elu+1
          unsigned short hb = f2bf_rne(v);
          h4[r] = hb;
          l4[r] = f2bf_rne(v - bf2f(hb));
        }
        if (c3 == 0){
          unsigned short* Qb = Q2 + ((size_t)hh * T_SEQ + gr0) * 128 + s;
          #pragma unroll
          for (int r = 0; r < 4; ++r){ Qb[(size_t)r * 128] = h4[r]; Qb[(size_t)r * 128 + 64] = l4[r]; }
        } else if (c3 == 1){
          unsigned short* Kb = K2k + ((size_t)hh * T_SEQ + gr0) * 128 + s;
          #pragma unroll
          for (int r = 0; r < 4; ++r){ Kb[(size_t)r * 128] = h4[r]; Kb[(size_t)r * 128 + 64] = l4[r]; }
          *(u16x4*)(kT2 + ((size_t)((hh * 64 + s) * 2 + 0)) * T_SEQ + gr0) = h4;
          *(u16x4*)(kT2 + ((size_t)((hh * 64 + s) * 2 + 1)) * T_SEQ + gr0) = l4;
        } else {
          *(u16x4*)(VT2 + ((size_t)((hh * 80 + s) * 2 + 0)) * T_SEQ + gr0) = h4;
          *(u16x4*)(VT2 + ((size_t)((hh * 80 + s) * 2 + 1)) * T_SEQ + gr0) = l4;
        }
      }
    }
  }
}

// ---------------------------------------------------------------------------
// Per-chunk St[f][d] = sum_t v[t][f] k[t][d]  (f=64 row -> z; 65..79 -> 0)
// MFMA NT pattern: A = VT2 rows f, B = kT2 rows d, K-dim = t (64).
// grid 512 (XCD-swizzled (h,c)), 4 waves; wave w owns d-tile [16w,16w+16).
// ---------------------------------------------------------------------------
__global__ __launch_bounds__(256)
void chunk_kv_mfma(const unsigned short* __restrict__ VT2,
                   const unsigned short* __restrict__ kT2,
                   float* __restrict__ Sc)
{
  const int bid = blockIdx.x;
  const int swz = (bid & 7) * 64 + (bid >> 3);
  const int h = swz >> 5, c = swz & 31;
  const int lane = threadIdx.x & 63, w = threadIdx.x >> 6;
  const int li = lane & 15, hq = lane >> 4;
  const int bt = c * 64;

  f32x4 acc[5];
  #pragma unroll
  for (int mt = 0; mt < 5; ++mt) acc[mt] = (f32x4)0.f;

  const unsigned short* Kb = kT2 + ((size_t)((h * 64 + 16 * w + li) * 2)) * T_SEQ + bt;
  u16x8 bh[2], bl[2];
  #pragma unroll
  for (int ks = 0; ks < 2; ++ks){
    bh[ks] = *(const u16x8*)(Kb + ks * 32 + hq * 8);
    bl[ks] = *(const u16x8*)(Kb + T_SEQ + ks * 32 + hq * 8);
  }
  #pragma unroll
  for (int mt = 0; mt < 5; ++mt){
    const unsigned short* Ab = VT2 + ((size_t)((h * 80 + 16 * mt + li) * 2)) * T_SEQ + bt;
    #pragma unroll
    for (int ks = 0; ks < 2; ++ks){
      u16x8 ah = *(const u16x8*)(Ab + ks * 32 + hq * 8);
      u16x8 al = *(const u16x8*)(Ab + T_SEQ + ks * 32 + hq * 8);
      mfma_bf16(acc[mt], ah, bh[ks]);
      mfma_bf16(acc[mt], ah, bl[ks]);
      mfma_bf16(acc[mt], al, bh[ks]);
    }
  }
  float* Sp = Sc + ((size_t)(h * 32 + c) * 80) * 64;
  #pragma unroll
  for (int mt = 0; mt < 5; ++mt){
    int f = 16 * mt + 4 * hq;
    #pragma unroll
    for (int r = 0; r < 4; ++r)
      Sp[(size_t)(f + r) * 64 + 16 * w + li] = acc[mt][r];
  }
}

// ---------------------------------------------------------------------------
// Exclusive prefix over chunks -> split-bf16 SpT2 [h][c][f][d_hi|d_lo].
// grid (16, 20): thread owns (f,d); f>64 writes zeros.
// ---------------------------------------------------------------------------
__global__ __launch_bounds__(256)
void scan_chunks2(const float* __restrict__ Sc, unsigned short* __restrict__ SpT2)
{
  const int h = blockIdx.x;
  const int e = blockIdx.y * 256 + threadIdx.x;   // 0..5119
  const int f = e >> 6, d = e & 63;
  unsigned short* Op = SpT2 + ((size_t)(h * 32) * 80 + f) * 128 + d;
  if (f > 64){
    for (int c = 0; c < NC; ++c){ Op[0] = 0; Op[64] = 0; Op += (size_t)80 * 128; }
    return;
  }
  const float* Ip = Sc + ((size_t)(h * 32) * 80 + f) * 64 + d;
  float run = 0.f;
  for (int c = 0; c < NC; ++c){
    unsigned short hb = f2bf_rne(run);
    Op[0]  = hb;
    Op[64] = f2bf_rne(run - bf2f(hb));
    run += Ip[0];
    Ip += (size_t)80 * 64;
    Op += (size_t)80 * 128;
  }
}

// ---------------------------------------------------------------------------
// MFMA chunk attention. Per (h,c), 4 waves; wave w owns i-rows [16w,16w+16).
//  m1: S = Q K^T (NT)  -> mask -> P split-bf16 to LDS
//  m3: O += Q Sp^T     (N=80: col 64 = q.z den part)  [independent of P]
//  m2: O += P V        (VT2 ones row 64 -> den intra part)
//  xo = O[:,0:64] / (O[:,64]+eps) -> XO2 split-bf16 [t][hi|lo]
// ---------------------------------------------------------------------------
__global__ __launch_bounds__(256)
void chunk_attn_mfma(const unsigned short* __restrict__ Q2,
                     const unsigned short* __restrict__ K2k,
                     const unsigned short* __restrict__ VT2,
                     const unsigned short* __restrict__ SpT2,
                     unsigned short* __restrict__ XO2)
{
  __shared__ unsigned short Pl[64][136];   // [i][j_hi64|j_lo64|pad8], 2-way banks
  const int bid = blockIdx.x;
  const int swz = (bid & 7) * 64 + (bid >> 3);
  const int h = swz >> 5, c = swz & 31;
  const int lane = threadIdx.x & 63, w = threadIdx.x >> 6;
  const int li = lane & 15, hq = lane >> 4;
  const int bt = c * 64;

  // q A-frags (rows 16w+li of this chunk) — reused by m1 and m3
  const unsigned short* Qp = Q2 + ((size_t)h * T_SEQ + bt + 16 * w + li) * 128;
  u16x8 qh[2], ql[2];
  #pragma unroll
  for (int ks = 0; ks < 2; ++ks){
    qh[ks] = *(const u16x8*)(Qp + ks * 32 + hq * 8);
    ql[ks] = *(const u16x8*)(Qp + 64 + ks * 32 + hq * 8);
  }

  // m1: S = Q K^T
  f32x4 accs[4];
  #pragma unroll
  for (int nt = 0; nt < 4; ++nt) accs[nt] = (f32x4)0.f;
  #pragma unroll
  for (int nt = 0; nt < 4; ++nt){
    const unsigned short* Kp = K2k + ((size_t)h * T_SEQ + bt + 16 * nt + li) * 128;
    #pragma unroll
    for (int ks = 0; ks < 2; ++ks){
      u16x8 kh = *(const u16x8*)(Kp + ks * 32 + hq * 8);
      u16x8 kl = *(const u16x8*)(Kp + 64 + ks * 32 + hq * 8);
      mfma_bf16(accs[nt], qh[ks], kh);
      mfma_bf16(accs[nt], qh[ks], kl);
      mfma_bf16(accs[nt], ql[ks], kh);
    }
  }

  // mask (j<=i) + split-bf16 P to LDS
  #pragma unroll
  for (int nt = 0; nt < 4; ++nt){
    int i0 = 16 * w + 4 * hq;
    int j  = 16 * nt + li;
    #pragma unroll
    for (int r = 0; r < 4; ++r){
      float v = (j <= i0 + r) ? accs[nt][r] : 0.f;
      unsigned short hb = f2bf_rne(v);
      Pl[i0 + r][j]      = hb;
      Pl[i0 + r][64 + j] = f2bf_rne(v - bf2f(hb));
    }
  }

  // m3: O += Q Sp^T  (independent of P — hides the barrier)
  f32x4 acco[5];
  #pragma unroll
  for (int nt = 0; nt < 5; ++nt) acco[nt] = (f32x4)0.f;
  const unsigned short* Sb = SpT2 + ((size_t)(h * 32 + c) * 80) * 128;
  #pragma unroll
  for (int nt = 0; nt < 5; ++nt){
    const unsigned short* Sp = Sb + (size_t)(16 * nt + li) * 128;
    #pragma unroll
    for (int ks = 0; ks < 2; ++ks){
      u16x8 sh = *(const u16x8*)(Sp + ks * 32 + hq * 8);
      u16x8 sl = *(const u16x8*)(Sp + 64 + ks * 32 + hq * 8);
      mfma_bf16(acco[nt], qh[ks], sh);
      mfma_bf16(acco[nt], qh[ks], sl);
      mfma_bf16(acco[nt], ql[ks], sh);
    }
  }

  __syncthreads();

  // P A-frags (rows 16w+li)
  u16x8 ph[2], plo[2];
  #pragma unroll
  for (int ks = 0; ks < 2; ++ks){
    ph[ks]  = *(const u16x8*)&Pl[16 * w + li][ks * 32 + hq * 8];
    plo[ks] = *(const u16x8*)&Pl[16 * w + li][64 + ks * 32 + hq * 8];
  }
  // m2: O += P V
  #pragma unroll
  for (int nt = 0; nt < 5; ++nt){
    const unsigned short* Vp = VT2 + ((size_t)((h * 80 + 16 * nt + li) * 2)) * T_SEQ + bt;
    #pragma unroll
    for (int ks = 0; ks < 2; ++ks){
      u16x8 vh = *(const u16x8*)(Vp + ks * 32 + hq * 8);
      u16x8 vl = *(const u16x8*)(Vp + T_SEQ + ks * 32 + hq * 8);
      mfma_bf16(acco[nt], ph[ks], vh);
      mfma_bf16(acco[nt], ph[ks], vl);
      mfma_bf16(acco[nt], plo[ks], vh);
    }
  }

  // epilogue: den = O[:,64] (held at li==0 of each quarter) -> broadcast
  float dv[4];
  #pragma unroll
  for (int r = 0; r < 4; ++r)
    dv[r] = __shfl(acco[4][r], (lane & 48));
  #pragma unroll
  for (int nt = 0; nt < 4; ++nt){
    int f = 16 * nt + li;
    #pragma unroll
    for (int r = 0; r < 4; ++r){
      int t = bt + 16 * w + 4 * hq + r;
      float val = acco[nt][r] / (dv[r] + 1e-6f);
      unsigned short hb = f2bf_rne(val);
      XO2[(size_t)t * K2 + h * 64 + f]           = hb;
      XO2[(size_t)t * K2 + D_MODEL + h * 64 + f] = f2bf_rne(val - bf2f(hb));
    }
  }
}

// ---------------------------------------------------------------------------
extern "C" void kernel_launch(void* const* d_in, const int* in_sizes, int n_in,
                              void* d_out, int out_size, void* d_ws, size_t ws_size,
                              hipStream_t stream)
{
  (void)in_sizes; (void)n_in; (void)out_size; (void)ws_size;
  const float* x     = (const float*)d_in[0];
  const float* w_qkv = (const float*)d_in[1];
  const float* w_out = (const float*)d_in[2];
  float* out = (float*)d_out;
  char* wsb = (char*)d_ws;
  const size_t MiB = (size_t)1 << 20;

  // workspace (~59 MiB peak), phase-disjoint aliasing:
  unsigned short* X2   = (unsigned short*)(wsb);              // [0,8)  g1 in
  unsigned short* Wq2  = (unsigned short*)(wsb + 8  * MiB);   // [8,20.58) g1 in
  float*          Sc   = (float*)(wsb);                       // [0,10) after g1
  unsigned short* SpT2 = (unsigned short*)(wsb + 10 * MiB);   // [10,20) after g1
  unsigned short* XO2  = (unsigned short*)(wsb);              // [0,8) after scan (Sc dead)
  unsigned short* Q2   = (unsigned short*)(wsb + 21 * MiB);   // [21,29)
  unsigned short* K2k  = (unsigned short*)(wsb + 29 * MiB);   // [29,37)
  unsigned short* kT2  = (unsigned short*)(wsb + 37 * MiB);   // [37,45)
  unsigned short* VT2  = (unsigned short*)(wsb + 45 * MiB);   // [45,55)
  unsigned short* Wo2  = (unsigned short*)(wsb + 55 * MiB);   // [55,59.2)

  split_all<<<6656, 256, 0, stream>>>(x, w_qkv, w_out, X2, Wq2, Wo2, VT2);
  // qkv = x @ w_qkv^T (+phi), emitted directly as MFMA operand layouts
  gemm_split3<128, 1><<<384, 256, 0, stream>>>(X2, Wq2, nullptr, 3072, Q2, K2k, kT2, VT2);
  chunk_kv_mfma<<<512, 256, 0, stream>>>(VT2, kT2, Sc);
  scan_chunks2<<<dim3(16, 20), 256, 0, stream>>>(Sc, SpT2);
  chunk_attn_mfma<<<512, 256, 0, stream>>>(Q2, K2k, VT2, SpT2, XO2);
  // out = xo @ w_out^T
  gemm_split3<64, 0><<<256, 256, 0, stream>>>(XO2, Wo2, out, 1024,
                                              nullptr, nullptr, nullptr, nullptr);
}